// Round 2
// baseline (197.509 us; speedup 1.0000x reference)
//
#include <hip/hip_runtime.h>
#include <math.h>

#define N_NODES 50000
#define N_EDGES 800000
#define EPS 1e-7f
#define NEG_SLOPE 0.01f

#define BUCKET 64                    // max records kept per node (Poisson mean 16)
#define GSTRIDE 72                   // bucket stride in records
#define FEAT_BLOCKS (N_NODES * 64 / 4 / 256)  // 3125 (4 floats per thread)
#define EDGE_BLOCKS (N_EDGES / 256)           // 3125
#define ACC_STRIDE 264               // bf16 elements per LDS acc row (256 + 8 pad)

typedef __attribute__((ext_vector_type(8))) short short8;
typedef __attribute__((ext_vector_type(4))) float f32x4;

// round-to-nearest-even bf16 (low 16 bits of result)
__device__ __forceinline__ unsigned bf16_rne(float x) {
    unsigned u = __float_as_uint(x);
    u += 0x7fffu + ((u >> 16) & 1u);
    return u >> 16;
}
__device__ __forceinline__ unsigned pack_bf16(float a, float b) {
    return bf16_rne(a) | (bf16_rne(b) << 16);
}

// ---------------- pass 1 (fused): feat/weight pack + edge bucketing ----------------
// hist part writes ONLY the 16-bit src id per record (2B scatter instead of 8B,
// no pos gathers). Geometry is recomputed lane-parallel (f32) in pass 2.

__global__ __launch_bounds__(256) void pack_hist_kernel(
    const float* __restrict__ feat, uint2* __restrict__ featb2,
    const float* __restrict__ W_neigh, const float* __restrict__ W_self,
    const float* __restrict__ b_neigh, const float* __restrict__ bias,
    unsigned* __restrict__ wnp, unsigned* __restrict__ wsp, float* __restrict__ bb,
    const int* __restrict__ src, const int* __restrict__ dst,
    int* __restrict__ cnt, unsigned short* __restrict__ gsrcs)
{
    const int bid = blockIdx.x;
    if (bid < FEAT_BLOCKS) {  // feat -> bf16 pack
        const int idx = bid * 256 + threadIdx.x;  // 0 .. 799999
        float4 v = reinterpret_cast<const float4*>(feat)[idx];
        featb2[idx] = make_uint2(pack_bf16(v.x, v.y), pack_bf16(v.z, v.w));
        return;
    }
    if (bid == FEAT_BLOCKS) {  // weight-pack block
        const int t = threadIdx.x;
        const float2* Wn2 = (const float2*)W_neigh;
        const float2* Ws2 = (const float2*)W_self;
        for (int i = t; i < 64 * 128; i += 256) {
            float2 v = Wn2[i];
            wnp[i] = pack_bf16(v.x, v.y);
        }
        for (int i = t; i < 64 * 32; i += 256) {
            float2 v = Ws2[i];
            wsp[i] = pack_bf16(v.x, v.y);
        }
        if (t < 64) bb[t] = b_neigh[t] + bias[t];
        return;
    }
    // edge bucketing: src-only 2B records
    const int i = (bid - FEAT_BLOCKS - 1) * 256 + threadIdx.x;  // 0 .. 799999
    const int s = src[i], d = dst[i];
    const int p = atomicAdd(&cnt[d], 1);
    if (p < BUCKET) gsrcs[(size_t)d * GSTRIDE + p] = (unsigned short)s;
}

// ---------------- pass 2: geometry prepass + fused aggregation + MFMA ----------------
// LDS record recG[r*GSTRIDE+e]: u.x = bf16(wx)|bf16(wy)<<16 ; u.y = bf16(wz)|src<<16

__device__ __forceinline__ float featload(const unsigned short* featb, unsigned rec_y,
                                          int lane) {
    // idx = src*64 + lane, all 32-bit math (src = rec_y>>16)
    const unsigned idx = ((rec_y >> 10) & 0x3FFFC0u) + (unsigned)lane;
    return __uint_as_float((unsigned)featb[idx] << 16);
}

__global__ __launch_bounds__(256) void aggregate_project_kernel(
    const unsigned short* __restrict__ featb, const float* __restrict__ W_sp,
    const float* __restrict__ b_sp, const int* __restrict__ cnt,
    const unsigned short* __restrict__ gsrcs, const float* __restrict__ pos,
    const short* __restrict__ wnb, const short* __restrict__ wsb,
    const float* __restrict__ bb, float* __restrict__ out)
{
    __shared__ unsigned short accS[16 * ACC_STRIDE];  // 8448 B
    __shared__ uint2 recG[16 * GSTRIDE];              // 9216 B (wave-private rows)

    const int lane = threadIdx.x & 63;
    const int w = threadIdx.x >> 6;
    const int nb = blockIdx.x << 4;  // 3125*16 == 50000 exact

    // per-lane spatial-MLP rows (f32): lane = feature i, handles j = lane*4+h
    float wsp0[4], wsp1[4], wsp2[4], bsp[4];
#pragma unroll
    for (int h = 0; h < 4; ++h) {
        int j = lane * 4 + h;
        wsp0[h] = W_sp[j * 3 + 0];
        wsp1[h] = W_sp[j * 3 + 1];
        wsp2[h] = W_sp[j * 3 + 2];
        bsp[h]  = b_sp[j];
    }

    // ---- geometry prepass: lane e builds record e of each of this wave's 4 nodes ----
    int degt[4];
#pragma unroll
    for (int q = 0; q < 4; ++q) {
        const int r = (w << 2) + q;
        const int n = nb + r;
        degt[q] = cnt[n];
        const int deg = min(degt[q], BUCKET);
        uint2 rec = make_uint2(0u, 0u);  // zero record: w*=0, src=0 (safe featload)
        if (lane < deg) {
            const int s = (int)gsrcs[(size_t)n * GSTRIDE + lane];  // coalesced 128B
            const float rx = pos[n * 3 + 0] - pos[s * 3 + 0];
            const float ry = pos[n * 3 + 1] - pos[s * 3 + 1];
            const float rz = pos[n * 3 + 2] - pos[s * 3 + 2];
            const float inv = __builtin_amdgcn_rcpf(
                __builtin_amdgcn_sqrtf(rx * rx + ry * ry + rz * rz) + EPS);
            rec = make_uint2(pack_bf16((rx + 1.f) * inv, (ry + 1.f) * inv),
                             bf16_rne((rz + 1.f) * inv) | ((unsigned)s << 16));
        }
        recG[r * GSTRIDE + lane] = rec;
        if (lane < 8) recG[r * GSTRIDE + 64 + lane] = make_uint2(0u, 0u);  // prefetch pad
    }

#define MLP_ACC(U, F)                                                              \
    {                                                                              \
        const float wx = __uint_as_float((U).x << 16);                             \
        const float wy = __uint_as_float((U).x & 0xffff0000u);                     \
        const float wz = __uint_as_float((U).y << 16);                             \
        float t0 = fmaf(wx, wsp0[0], fmaf(wy, wsp1[0], fmaf(wz, wsp2[0], bsp[0])));\
        float t1 = fmaf(wx, wsp0[1], fmaf(wy, wsp1[1], fmaf(wz, wsp2[1], bsp[1])));\
        float t2 = fmaf(wx, wsp0[2], fmaf(wy, wsp1[2], fmaf(wz, wsp2[2], bsp[2])));\
        float t3 = fmaf(wx, wsp0[3], fmaf(wy, wsp1[3], fmaf(wz, wsp2[3], bsp[3])));\
        a0 = fmaf(fmaxf(t0, t0 * NEG_SLOPE), (F), a0);                             \
        a1 = fmaf(fmaxf(t1, t1 * NEG_SLOPE), (F), a1);                             \
        a2 = fmaf(fmaxf(t2, t2 * NEG_SLOPE), (F), a2);                             \
        a3 = fmaf(fmaxf(t3, t3 * NEG_SLOPE), (F), a3);                             \
    }

    // ---- aggregation: wave w handles rows 4w..4w+3, one node at a time ----
#pragma unroll
    for (int q = 0; q < 4; ++q) {
        const int r = (w << 2) + q;
        const int dt = __builtin_amdgcn_readfirstlane(degt[q]);
        const int deg = min(dt, BUCKET);
        const uint2* gp = &recG[r * GSTRIDE];  // LDS, broadcast reads

        float a0 = 0.f, a1 = 0.f, a2 = 0.f, a3 = 0.f;

        if (deg > 0) {
            const int dm = deg - 1;
            uint2 u0 = gp[0];
            uint2 u1 = gp[1];
            float f0 = featload(featb, u0.y, lane);
            float f1 = featload(featb, u1.y, lane);

            for (int e = 0; e < deg; e += 2) {
                uint2 u2 = gp[e + 2];  // unclamped: e+3 <= 66 < 72, pad slots zeroed
                uint2 u3 = gp[e + 3];
                float f2 = featload(featb, u2.y, lane);
                float f3 = featload(featb, u3.y, lane);

                MLP_ACC(u0, f0)
                {
                    const float fm = (e + 1 <= dm) ? f1 : 0.f;
                    MLP_ACC(u1, fm)
                }

                u0 = u2; u1 = u3;
                f0 = f2; f1 = f3;
            }
        }

        const float mscale = 1.f / fmaxf((float)dt, 1.f);
        uint2 pv = make_uint2(pack_bf16(a0 * mscale, a1 * mscale),
                              pack_bf16(a2 * mscale, a3 * mscale));
        *reinterpret_cast<uint2*>(&accS[r * ACC_STRIDE + lane * 4]) = pv;
    }
#undef MLP_ACC
    __syncthreads();

    // ---- projection: wave w -> output col-tile w (cols w*16..w*16+15) ----
    const int mrow = lane & 15;
    const int quad = lane >> 4;
    const int o = (w << 4) + mrow;

    f32x4 acc = {0.f, 0.f, 0.f, 0.f};

    const unsigned short* Ar = &accS[mrow * ACC_STRIDE + quad * 8];
    const short* Br = wnb + o * 256 + quad * 8;
#pragma unroll
    for (int ks = 0; ks < 8; ++ks) {
        short8 a = *reinterpret_cast<const short8*>(Ar + ks * 32);
        short8 b = *reinterpret_cast<const short8*>(Br + ks * 32);
        acc = __builtin_amdgcn_mfma_f32_16x16x32_bf16(a, b, acc, 0, 0, 0);
    }

    const short* Fr = (const short*)featb + (size_t)(nb + mrow) * 64 + quad * 8;
    const short* Sr = wsb + o * 64 + quad * 8;
#pragma unroll
    for (int ks = 0; ks < 2; ++ks) {
        short8 a = *reinterpret_cast<const short8*>(Fr + ks * 32);
        short8 b = *reinterpret_cast<const short8*>(Sr + ks * 32);
        acc = __builtin_amdgcn_mfma_f32_16x16x32_bf16(a, b, acc, 0, 0, 0);
    }

    const float badd = bb[o];
#pragma unroll
    for (int r = 0; r < 4; ++r) {
        out[(size_t)(nb + quad * 4 + r) * 64 + o] = acc[r] + badd;
    }
}

// ---------------- launch ----------------

extern "C" void kernel_launch(void* const* d_in, const int* in_sizes, int n_in,
                              void* d_out, int out_size, void* d_ws, size_t ws_size,
                              hipStream_t stream) {
    (void)in_sizes; (void)n_in; (void)out_size; (void)ws_size;
    const float* feat    = (const float*)d_in[0];
    const float* pos     = (const float*)d_in[1];
    const int*   src     = (const int*)d_in[2];
    const int*   dst     = (const int*)d_in[3];
    const float* W_self  = (const float*)d_in[4];
    const float* W_sp    = (const float*)d_in[5];
    const float* b_sp    = (const float*)d_in[6];
    const float* W_neigh = (const float*)d_in[7];
    const float* b_neigh = (const float*)d_in[8];
    const float* bias    = (const float*)d_in[9];
    float* out = (float*)d_out;

    // ws layout: gsrcs[N*72] ushort (7.2 MB) | featb2[800000] uint2 (6.4 MB) |
    //            wnp[8192] | wsp[2048] | bb[64]f | cnt[N]
    unsigned short* gsrcs  = (unsigned short*)d_ws;
    uint2*          featb2 = (uint2*)(gsrcs + (size_t)N_NODES * GSTRIDE);  // 8B-aligned
    unsigned int*   wnp    = (unsigned int*)(featb2 + 800000);
    unsigned int*   wsp    = wnp + 8192;
    float*          bb     = (float*)(wsp + 2048);
    int*            cnt    = (int*)(bb + 64);

    hipMemsetAsync(cnt, 0, (size_t)N_NODES * sizeof(int), stream);
    pack_hist_kernel<<<FEAT_BLOCKS + 1 + EDGE_BLOCKS, 256, 0, stream>>>(
        feat, featb2, W_neigh, W_self, b_neigh, bias, wnp, wsp, bb,
        src, dst, cnt, gsrcs);
    aggregate_project_kernel<<<N_NODES / 16, 256, 0, stream>>>(
        (const unsigned short*)featb2, W_sp, b_sp, cnt, gsrcs, pos,
        (const short*)wnp, (const short*)wsp, bb, out);
}

// Round 3
// 186.337 us; speedup vs baseline: 1.0600x; 1.0600x over previous
//
#include <hip/hip_runtime.h>
#include <math.h>

#define N_NODES 50000
#define N_EDGES 800000
#define EPS 1e-7f
#define NEG_SLOPE 0.01f

#define BUCKET 64                    // max records kept per node (Poisson mean 16)
#define GSTRIDE 72                   // bucket stride in records (2B each)
#define CSTRIDE 16                   // ints per counter slot: 64B line per node
#define FEAT_BLOCKS (N_NODES * 64 / 4 / 256)  // 3125 (4 floats per thread)
#define EDGE_BLOCKS4 782             // ceil(800000 / (256*4))
#define ACC_STRIDE 264               // bf16 elements per LDS acc row (256 + 8 pad)

typedef __attribute__((ext_vector_type(8))) short short8;
typedef __attribute__((ext_vector_type(4))) float f32x4;

// round-to-nearest-even bf16 (low 16 bits of result)
__device__ __forceinline__ unsigned bf16_rne(float x) {
    unsigned u = __float_as_uint(x);
    u += 0x7fffu + ((u >> 16) & 1u);
    return u >> 16;
}
__device__ __forceinline__ unsigned pack_bf16(float a, float b) {
    return bf16_rne(a) | (bf16_rne(b) << 16);
}

// ---------------- pass 1 (fused): feat/weight pack + edge bucketing ----------------
// Records are 16-bit src ids only. Counters padded to 64B/node to kill the
// same-line coherence serialization (16 counters/line x 16 hits = 256 serialized
// ops per line was the round-2 bottleneck: 75us at 0.7% VALU, 10% HBM).

__global__ __launch_bounds__(256) void pack_hist_kernel(
    const float* __restrict__ feat, uint2* __restrict__ featb2,
    const float* __restrict__ W_neigh, const float* __restrict__ W_self,
    const float* __restrict__ b_neigh, const float* __restrict__ bias,
    unsigned* __restrict__ wnp, unsigned* __restrict__ wsp, float* __restrict__ bb,
    const int* __restrict__ src, const int* __restrict__ dst,
    int* __restrict__ cnt, unsigned short* __restrict__ gsrcs)
{
    const int bid = blockIdx.x;
    if (bid < FEAT_BLOCKS) {  // feat -> bf16 pack
        const int idx = bid * 256 + threadIdx.x;  // 0 .. 799999
        float4 v = reinterpret_cast<const float4*>(feat)[idx];
        featb2[idx] = make_uint2(pack_bf16(v.x, v.y), pack_bf16(v.z, v.w));
        return;
    }
    if (bid == FEAT_BLOCKS) {  // weight-pack block
        const int t = threadIdx.x;
        const float2* Wn2 = (const float2*)W_neigh;
        const float2* Ws2 = (const float2*)W_self;
        for (int i = t; i < 64 * 128; i += 256) {
            float2 v = Wn2[i];
            wnp[i] = pack_bf16(v.x, v.y);
        }
        for (int i = t; i < 64 * 32; i += 256) {
            float2 v = Ws2[i];
            wsp[i] = pack_bf16(v.x, v.y);
        }
        if (t < 64) bb[t] = b_neigh[t] + bias[t];
        return;
    }
    // edge bucketing: 4 edges per thread, int4 coalesced loads, independent
    // atomic chains for latency hiding
    const int base = (bid - FEAT_BLOCKS - 1) * 1024 + threadIdx.x * 4;
    if (base >= N_EDGES) return;  // 800000 % 4 == 0, so base<N => base+3<N
    const int4 s4 = *reinterpret_cast<const int4*>(src + base);
    const int4 d4 = *reinterpret_cast<const int4*>(dst + base);
#define EDGE_PUT(S, D)                                                        \
    {                                                                         \
        const int p = atomicAdd(&cnt[(D) * CSTRIDE], 1);                      \
        if (p < BUCKET)                                                       \
            __builtin_nontemporal_store((unsigned short)(S),                  \
                                        &gsrcs[(size_t)(D) * GSTRIDE + p]);   \
    }
    EDGE_PUT(s4.x, d4.x)
    EDGE_PUT(s4.y, d4.y)
    EDGE_PUT(s4.z, d4.z)
    EDGE_PUT(s4.w, d4.w)
#undef EDGE_PUT
}

// ---------------- pass 2: geometry prepass + fused aggregation + MFMA ----------------
// LDS record recG[r*GSTRIDE+e]: u.x = bf16(wx)|bf16(wy)<<16 ; u.y = bf16(wz)|src<<16

__device__ __forceinline__ float featload(const unsigned short* featb, unsigned rec_y,
                                          int lane) {
    // idx = src*64 + lane, all 32-bit math (src = rec_y>>16)
    const unsigned idx = ((rec_y >> 10) & 0x3FFFC0u) + (unsigned)lane;
    return __uint_as_float((unsigned)featb[idx] << 16);
}

__global__ __launch_bounds__(256) void aggregate_project_kernel(
    const unsigned short* __restrict__ featb, const float* __restrict__ W_sp,
    const float* __restrict__ b_sp, const int* __restrict__ cnt,
    const unsigned short* __restrict__ gsrcs, const float* __restrict__ pos,
    const short* __restrict__ wnb, const short* __restrict__ wsb,
    const float* __restrict__ bb, float* __restrict__ out)
{
    __shared__ unsigned short accS[16 * ACC_STRIDE];  // 8448 B
    __shared__ uint2 recG[16 * GSTRIDE];              // 9216 B (wave-private rows)

    const int lane = threadIdx.x & 63;
    const int w = threadIdx.x >> 6;
    const int nb = blockIdx.x << 4;  // 3125*16 == 50000 exact

    // per-lane spatial-MLP rows (f32): lane = feature i, handles j = lane*4+h
    float wsp0[4], wsp1[4], wsp2[4], bsp[4];
#pragma unroll
    for (int h = 0; h < 4; ++h) {
        int j = lane * 4 + h;
        wsp0[h] = W_sp[j * 3 + 0];
        wsp1[h] = W_sp[j * 3 + 1];
        wsp2[h] = W_sp[j * 3 + 2];
        bsp[h]  = b_sp[j];
    }

    // ---- geometry prepass: lane e builds record e of each of this wave's 4 nodes ----
    int degt[4];
#pragma unroll
    for (int q = 0; q < 4; ++q) {
        const int r = (w << 2) + q;
        const int n = nb + r;
        degt[q] = cnt[n * CSTRIDE];
        const int deg = min(degt[q], BUCKET);
        uint2 rec = make_uint2(0u, 0u);  // zero record: w*=0, src=0 (safe featload)
        if (lane < deg) {
            const int s = (int)gsrcs[(size_t)n * GSTRIDE + lane];  // coalesced 128B
            const float rx = pos[n * 3 + 0] - pos[s * 3 + 0];
            const float ry = pos[n * 3 + 1] - pos[s * 3 + 1];
            const float rz = pos[n * 3 + 2] - pos[s * 3 + 2];
            const float inv = __builtin_amdgcn_rcpf(
                __builtin_amdgcn_sqrtf(rx * rx + ry * ry + rz * rz) + EPS);
            rec = make_uint2(pack_bf16((rx + 1.f) * inv, (ry + 1.f) * inv),
                             bf16_rne((rz + 1.f) * inv) | ((unsigned)s << 16));
        }
        recG[r * GSTRIDE + lane] = rec;
        if (lane < 8) recG[r * GSTRIDE + 64 + lane] = make_uint2(0u, 0u);  // prefetch pad
    }

#define MLP_ACC(U, F)                                                              \
    {                                                                              \
        const float wx = __uint_as_float((U).x << 16);                             \
        const float wy = __uint_as_float((U).x & 0xffff0000u);                     \
        const float wz = __uint_as_float((U).y << 16);                             \
        float t0 = fmaf(wx, wsp0[0], fmaf(wy, wsp1[0], fmaf(wz, wsp2[0], bsp[0])));\
        float t1 = fmaf(wx, wsp0[1], fmaf(wy, wsp1[1], fmaf(wz, wsp2[1], bsp[1])));\
        float t2 = fmaf(wx, wsp0[2], fmaf(wy, wsp1[2], fmaf(wz, wsp2[2], bsp[2])));\
        float t3 = fmaf(wx, wsp0[3], fmaf(wy, wsp1[3], fmaf(wz, wsp2[3], bsp[3])));\
        a0 = fmaf(fmaxf(t0, t0 * NEG_SLOPE), (F), a0);                             \
        a1 = fmaf(fmaxf(t1, t1 * NEG_SLOPE), (F), a1);                             \
        a2 = fmaf(fmaxf(t2, t2 * NEG_SLOPE), (F), a2);                             \
        a3 = fmaf(fmaxf(t3, t3 * NEG_SLOPE), (F), a3);                             \
    }

    // ---- aggregation: wave w handles rows 4w..4w+3, one node at a time ----
#pragma unroll
    for (int q = 0; q < 4; ++q) {
        const int r = (w << 2) + q;
        const int dt = __builtin_amdgcn_readfirstlane(degt[q]);
        const int deg = min(dt, BUCKET);
        const uint2* gp = &recG[r * GSTRIDE];  // LDS, broadcast reads

        float a0 = 0.f, a1 = 0.f, a2 = 0.f, a3 = 0.f;

        if (deg > 0) {
            const int dm = deg - 1;
            uint2 u0 = gp[0];
            uint2 u1 = gp[1];
            float f0 = featload(featb, u0.y, lane);
            float f1 = featload(featb, u1.y, lane);

            for (int e = 0; e < deg; e += 2) {
                uint2 u2 = gp[e + 2];  // unclamped: e+3 <= 66 < 72, pad slots zeroed
                uint2 u3 = gp[e + 3];
                float f2 = featload(featb, u2.y, lane);
                float f3 = featload(featb, u3.y, lane);

                MLP_ACC(u0, f0)
                {
                    const float fm = (e + 1 <= dm) ? f1 : 0.f;
                    MLP_ACC(u1, fm)
                }

                u0 = u2; u1 = u3;
                f0 = f2; f1 = f3;
            }
        }

        const float mscale = 1.f / fmaxf((float)dt, 1.f);
        uint2 pv = make_uint2(pack_bf16(a0 * mscale, a1 * mscale),
                              pack_bf16(a2 * mscale, a3 * mscale));
        *reinterpret_cast<uint2*>(&accS[r * ACC_STRIDE + lane * 4]) = pv;
    }
#undef MLP_ACC
    __syncthreads();

    // ---- projection: wave w -> output col-tile w (cols w*16..w*16+15) ----
    const int mrow = lane & 15;
    const int quad = lane >> 4;
    const int o = (w << 4) + mrow;

    f32x4 acc = {0.f, 0.f, 0.f, 0.f};

    const unsigned short* Ar = &accS[mrow * ACC_STRIDE + quad * 8];
    const short* Br = wnb + o * 256 + quad * 8;
#pragma unroll
    for (int ks = 0; ks < 8; ++ks) {
        short8 a = *reinterpret_cast<const short8*>(Ar + ks * 32);
        short8 b = *reinterpret_cast<const short8*>(Br + ks * 32);
        acc = __builtin_amdgcn_mfma_f32_16x16x32_bf16(a, b, acc, 0, 0, 0);
    }

    const short* Fr = (const short*)featb + (size_t)(nb + mrow) * 64 + quad * 8;
    const short* Sr = wsb + o * 64 + quad * 8;
#pragma unroll
    for (int ks = 0; ks < 2; ++ks) {
        short8 a = *reinterpret_cast<const short8*>(Fr + ks * 32);
        short8 b = *reinterpret_cast<const short8*>(Sr + ks * 32);
        acc = __builtin_amdgcn_mfma_f32_16x16x32_bf16(a, b, acc, 0, 0, 0);
    }

    const float badd = bb[o];
#pragma unroll
    for (int r = 0; r < 4; ++r) {
        out[(size_t)(nb + quad * 4 + r) * 64 + o] = acc[r] + badd;
    }
}

// ---------------- launch ----------------

extern "C" void kernel_launch(void* const* d_in, const int* in_sizes, int n_in,
                              void* d_out, int out_size, void* d_ws, size_t ws_size,
                              hipStream_t stream) {
    (void)in_sizes; (void)n_in; (void)out_size; (void)ws_size;
    const float* feat    = (const float*)d_in[0];
    const float* pos     = (const float*)d_in[1];
    const int*   src     = (const int*)d_in[2];
    const int*   dst     = (const int*)d_in[3];
    const float* W_self  = (const float*)d_in[4];
    const float* W_sp    = (const float*)d_in[5];
    const float* b_sp    = (const float*)d_in[6];
    const float* W_neigh = (const float*)d_in[7];
    const float* b_neigh = (const float*)d_in[8];
    const float* bias    = (const float*)d_in[9];
    float* out = (float*)d_out;

    // ws layout: gsrcs[N*72] ushort (7.2 MB) | featb2[800000] uint2 (6.4 MB) |
    //            wnp[8192] | wsp[2048] | bb[64]f | cnt[N*16] (3.2 MB, 64B/node)
    unsigned short* gsrcs  = (unsigned short*)d_ws;
    uint2*          featb2 = (uint2*)(gsrcs + (size_t)N_NODES * GSTRIDE);  // 8B-aligned
    unsigned int*   wnp    = (unsigned int*)(featb2 + 800000);
    unsigned int*   wsp    = wnp + 8192;
    float*          bb     = (float*)(wsp + 2048);
    int*            cnt    = (int*)(bb + 64);

    hipMemsetAsync(cnt, 0, (size_t)N_NODES * CSTRIDE * sizeof(int), stream);
    pack_hist_kernel<<<FEAT_BLOCKS + 1 + EDGE_BLOCKS4, 256, 0, stream>>>(
        feat, featb2, W_neigh, W_self, b_neigh, bias, wnp, wsp, bb,
        src, dst, cnt, gsrcs);
    aggregate_project_kernel<<<N_NODES / 16, 256, 0, stream>>>(
        (const unsigned short*)featb2, W_sp, b_sp, cnt, gsrcs, pos,
        (const short*)wnp, (const short*)wsp, bb, out);
}